// Round 6
// baseline (428.018 us; speedup 1.0000x reference)
//
#include <hip/hip_runtime.h>
#include <hip/hip_bf16.h>

typedef unsigned short u16;
typedef __attribute__((ext_vector_type(4))) unsigned short u16x4;
typedef __attribute__((ext_vector_type(8))) unsigned short u16x8;
typedef __attribute__((ext_vector_type(8))) __bf16 bf16x8;
typedef __attribute__((ext_vector_type(4))) float f32x4;

#define BB 16
#define TSEQ 1024
#define CC 584          /* embed dim */
#define HH 8
#define DHD 73
#define NR (BB*TSEQ)    /* 16384 rows */
#define KPW 608         /* padded K (19*32) — uniform GEMM K-loop */
#define KIT 19
#define DP 96           /* padded head dim */
#define HD (HH*DP)      /* 768 */
#define NP3 640         /* padded N for final proj */
/* exp(s*584^-0.5) == exp2(s * CEXP); scores bounded -> no max subtraction */
#define CEXP 0.0596985934f

__device__ __forceinline__ u16 f2bf(float f) {
  __bf16 h = (__bf16)f;                 // native v_cvt on gfx950, RNE
  return __builtin_bit_cast(u16, h);
}
__device__ __forceinline__ bf16x8 as_bf(u16x8 v) { return __builtin_bit_cast(bf16x8, v); }

/* async global->LDS, 16B/lane, LDS dst = wave-uniform base + lane*16 */
#define GLL16(g, l) __builtin_amdgcn_global_load_lds( \
    (const __attribute__((address_space(1))) void*)(g), \
    (__attribute__((address_space(3))) void*)(l), 16, 0, 0)

// ---------------- fused pack kernel (rebuilt every launch; ws is poisoned) -----------
// phase A (9728 blocks):  x|mem [16384,584] f32 -> xmb [32768][608] bf16 zero-padded
// phase B (5472 blocks):  Wq/Wv/Wk -> wt [q 768 | v 768 | k 768 rows][608] bf16
// phase C (1520 blocks):  Wp -> wpt [640][608] bf16 (transposed)
#define PKA 9728
#define PKB 5472
#define PKC 1520
__global__ void pack_all_kernel(const float* __restrict__ x, const float* __restrict__ mem,
                                const float* __restrict__ Wq, const float* __restrict__ Wk,
                                const float* __restrict__ Wv, const float* __restrict__ Wp,
                                u16* __restrict__ xmb, u16* __restrict__ wt,
                                u16* __restrict__ wpt) {
  const int bidx = blockIdx.x;
  const int tid = threadIdx.x;
  if (bidx < PKA) {
    int idx = bidx * 256 + tid;               // u16x8 groups, exactly 2*NR*(KPW/8)
    int row = idx / (KPW / 8);
    int c8  = (idx % (KPW / 8)) * 8;
    u16x8 o = {0, 0, 0, 0, 0, 0, 0, 0};
    if (c8 < CC) {
      const float* src = (row < NR) ? &x[(size_t)row * CC + c8]
                                    : &mem[(size_t)(row - NR) * CC + c8];
      f32x4 a = *(const f32x4*)src;
      f32x4 b = *(const f32x4*)(src + 4);
#pragma unroll
      for (int t = 0; t < 4; t++) { o[t] = f2bf(a[t]); o[4 + t] = f2bf(b[t]); }
    }
    *(u16x8*)&xmb[(size_t)row * KPW + c8] = o;
  } else if (bidx < PKA + PKB) {
    int idx = (bidx - PKA) * 256 + tid;       // exactly 3*HD*KPW
    int w   = idx / (HD * KPW);
    int rem = idx % (HD * KPW);
    int n = rem / KPW;
    int k = rem % KPW;
    int h = n / DP, d = n % DP;
    u16 val = 0;
    if (d < DHD && k < CC) {
      const float* W = (w == 0) ? Wq : ((w == 1) ? Wv : Wk);  // order: q, v, k
      val = f2bf(W[((size_t)h * CC + k) * DHD + d]);
    }
    wt[idx] = val;
  } else {
    int idx = (bidx - PKA - PKB) * 256 + tid; // exactly NP3*KPW
    int n = idx / KPW;
    int c = idx % KPW;
    u16 val = 0;
    if (n < CC && c < CC) val = f2bf(Wp[(size_t)c * CC + n]);
    wpt[idx] = val;
  }
}

// ---------------- bf16 GEMM (m97 structure): C[m][n] = sum_k A[m][k]*Bt[n][k] ----------
// A, Bt bf16 with row pitch KPW (zero-padded); uniform 19-iter K-loop.
// Staging via global_load_lds width=16. Grid: x = m-tile (fast), y = n-tile.
// MODE 0: store bf16 row-major [M][768]
// MODE 2: bias add, guard n < 584, store f32 [M][584]
// MODE 3: fused q+v: n-tiles 0..5 -> q row-major [M][768] into Cout;
//                    n-tiles 6..11 -> v transposed Cout2[(b*768+vn)*1024 + t]
template <int MODE>
__global__ __launch_bounds__(256) void gemm_bt_kernel(
    const u16* __restrict__ A, const u16* __restrict__ Bt,
    void* __restrict__ CoutV, void* __restrict__ CoutV2,
    const float* __restrict__ bias) {
  __shared__ u16 As[128 * 32];
  __shared__ u16 Bs[128 * 32];
  const int tid  = threadIdx.x;
  const int lane = tid & 63;
  const int wave = tid >> 6;
  const int m0 = blockIdx.x * 128;
  const int n0 = blockIdx.y * 128;
  const int wm = (wave >> 1) * 64;
  const int wn = (wave & 1) * 64;
  const int q15  = lane & 15;
  const int quad = lane >> 4;

  f32x4 acc[4][4];
#pragma unroll
  for (int i = 0; i < 4; i++)
#pragma unroll
    for (int j = 0; j < 4; j++) acc[i][j] = (f32x4){0.f, 0.f, 0.f, 0.f};

  const int r0 = tid >> 2;
  const int c0 = (tid & 3) * 8;
  u16* asd0 = &As[wave * 512];
  u16* asd1 = &As[2048 + wave * 512];
  u16* bsd0 = &Bs[wave * 512];
  u16* bsd1 = &Bs[2048 + wave * 512];
  const u16* gA0 = &A[(size_t)(m0 + r0) * KPW + c0];
  const u16* gA1 = gA0 + (size_t)64 * KPW;
  const u16* gB0 = &Bt[(size_t)(n0 + r0) * KPW + c0];
  const u16* gB1 = gB0 + (size_t)64 * KPW;

  for (int kk = 0; kk < KIT; ++kk) {
    GLL16(gA0, asd0);
    GLL16(gA1, asd1);
    GLL16(gB0, bsd0);
    GLL16(gB1, bsd1);
    gA0 += 32; gA1 += 32; gB0 += 32; gB1 += 32;
    __syncthreads();
    bf16x8 af[4], bfr[4];
#pragma unroll
    for (int i = 0; i < 4; i++)
      af[i] = as_bf(*(const u16x8*)&As[(wm + i * 16 + q15) * 32 + quad * 8]);
#pragma unroll
    for (int j = 0; j < 4; j++)
      bfr[j] = as_bf(*(const u16x8*)&Bs[(wn + j * 16 + q15) * 32 + quad * 8]);
#pragma unroll
    for (int i = 0; i < 4; i++)
#pragma unroll
      for (int j = 0; j < 4; j++)
        acc[i][j] = __builtin_amdgcn_mfma_f32_16x16x32_bf16(af[i], bfr[j], acc[i][j], 0, 0, 0);
    __syncthreads();
  }

#pragma unroll
  for (int i = 0; i < 4; i++) {
#pragma unroll
    for (int j = 0; j < 4; j++) {
      const int row = m0 + wm + i * 16 + quad * 4;
      const int col = n0 + wn + j * 16 + q15;
      if (MODE == 0) {
        u16* Cout = (u16*)CoutV;
#pragma unroll
        for (int r = 0; r < 4; r++)
          Cout[(size_t)(row + r) * HD + col] = f2bf(acc[i][j][r]);
      } else if (MODE == 3) {
        if (col < HD) {
          u16* Cout = (u16*)CoutV;
#pragma unroll
          for (int r = 0; r < 4; r++)
            Cout[(size_t)(row + r) * HD + col] = f2bf(acc[i][j][r]);
        } else {
          u16* Cout = (u16*)CoutV2;
          const int vn = col - HD;
          const int b  = row >> 10;
          const int tl = row & 1023;
          u16x4 pk;
#pragma unroll
          for (int r = 0; r < 4; r++) pk[r] = f2bf(acc[i][j][r]);
          *(u16x4*)&Cout[((size_t)(b * HD + vn)) * TSEQ + tl] = pk;
        }
      } else {
        if (col < CC) {
          float* Cout = (float*)CoutV;
          const float bv = bias[col];
#pragma unroll
          for (int r = 0; r < 4; r++)
            Cout[(size_t)(row + r) * CC + col] = acc[i][j][r] + bv;
        }
      }
    }
  }
}

// ---------------- barrier-free flash attention: per (b,h,128-row q tile) -------------
// Q/K/V MFMA fragments loaded DIRECTLY from global (16B/lane, L2-resident via XCD
// swizzle) — no LDS staging, no __syncthreads in the K-loop. Only the P round-trip
// uses LDS (wave-private Pt, same-wave in-order DS pipe). S^T = K·Q^T per wave so
// P stores are u16x4 vectors. Row-sums deferred to epilogue (scores bounded).
// q,k: [B,T,768] bf16 ; vt: [B,768,T] bf16 ; out attn: [16384][608] bf16 padded
__global__ __launch_bounds__(256, 2) void attn_kernel(
    const u16* __restrict__ qb, const u16* __restrict__ kb,
    const u16* __restrict__ vt, u16* __restrict__ attn) {
  __shared__ u16 Pt[4 * 32 * 76];       // per-wave [32 q][pitch 76]

  const int tid  = threadIdx.x;
  const int lane = tid & 63;
  const int wave = tid >> 6;
  const int q15  = lane & 15;
  const int quad = lane >> 4;
  // XCD swizzle: bid%8 = XCD; all 8 t-tiles of one (b,h) on the same XCD
  const int bid  = blockIdx.x;
  const int loc  = bid >> 3;
  const int pair = (bid & 7) * 16 + (loc >> 3);
  const int b  = pair >> 3;
  const int h  = pair & 7;
  const int t0 = (loc & 7) * 128;
  const int wq0 = wave * 32;

  // zero pad cols 584..607 of this block's output rows
  if (tid < 128) {
    const u16x8 z = {0, 0, 0, 0, 0, 0, 0, 0};
    size_t base = (size_t)(b * TSEQ + t0 + tid) * KPW + CC;
    *(u16x8*)&attn[base] = z;
    *(u16x8*)&attn[base + 8] = z;
    *(u16x8*)&attn[base + 16] = z;
  }

  // Q fragments (B-operand of S^T): aq[n][kc][j] = Q[t0+wq0+n*16+q15][kc*32+quad*8+j]
  bf16x8 aq[2][3];
#pragma unroll
  for (int n = 0; n < 2; n++)
#pragma unroll
    for (int kc = 0; kc < 3; kc++)
      aq[n][kc] = as_bf(*(const u16x8*)&qb[
          (size_t)(b * TSEQ + t0 + wq0 + n * 16 + q15) * HD + h * DP + kc * 32 + quad * 8]);

  // per-lane base pointers for K / V^T fragment loads
  const u16* kptr = &kb[(size_t)(b * TSEQ + q15) * HD + h * DP + quad * 8];
  const u16* vptr = &vt[(size_t)(b * HD + h * DP + q15) * TSEQ + quad * 8];

  float lsum[2] = {0.f, 0.f};
  f32x4 oacc[2][6];
#pragma unroll
  for (int m = 0; m < 2; m++)
#pragma unroll
    for (int jd = 0; jd < 6; jd++) oacc[m][jd] = (f32x4){0.f, 0.f, 0.f, 0.f};

  u16* Ptw = &Pt[wave * 32 * 76];

  for (int si = 0; si < 16; ++si) {
    const int s0 = si * 64;
    // K fragments (A-operand): ak[mt][kc][j] = K[s0+mt*16+q15][kc*32+quad*8+j]
    u16x8 ak[4][3];
#pragma unroll
    for (int mt = 0; mt < 4; mt++)
#pragma unroll
      for (int kc = 0; kc < 3; kc++)
        ak[mt][kc] = *(const u16x8*)&kptr[(size_t)(s0 + mt * 16) * HD + kc * 32];

    // S^T = K Q^T : C rows = s (4 tiles), cols = q (2 tiles)
    f32x4 st[4][2];
#pragma unroll
    for (int mt = 0; mt < 4; mt++)
#pragma unroll
      for (int n = 0; n < 2; n++) st[mt][n] = (f32x4){0.f, 0.f, 0.f, 0.f};
#pragma unroll
    for (int kc = 0; kc < 3; kc++)
#pragma unroll
      for (int mt = 0; mt < 4; mt++)
#pragma unroll
        for (int n = 0; n < 2; n++)
          st[mt][n] = __builtin_amdgcn_mfma_f32_16x16x32_bf16(
              as_bf(ak[mt][kc]), aq[n][kc], st[mt][n], 0, 0, 0);

    // V^T fragments (B-operand of PV): av[jd][kc][j] = V^T[jd*16+q15][s0+kc*32+quad*8+j]
    u16x8 av[6][2];
#pragma unroll
    for (int jd = 0; jd < 6; jd++)
#pragma unroll
      for (int kc = 0; kc < 2; kc++)
        av[jd][kc] = *(const u16x8*)&vptr[(size_t)(jd * 16) * TSEQ + s0 + kc * 32];

    // p = exp2(s*CEXP); per-lane partial row sums; vectorized Pt store (wave-private)
#pragma unroll
    for (int mt = 0; mt < 4; mt++)
#pragma unroll
      for (int n = 0; n < 2; n++) {
        f32x4 pv;
#pragma unroll
        for (int r = 0; r < 4; r++) pv[r] = __builtin_amdgcn_exp2f(st[mt][n][r] * CEXP);
        lsum[n] += (pv[0] + pv[1]) + (pv[2] + pv[3]);
        u16x4 pk;
#pragma unroll
        for (int r = 0; r < 4; r++) pk[r] = f2bf(pv[r]);
        *(u16x4*)&Ptw[(n * 16 + q15) * 76 + mt * 16 + quad * 4] = pk;
      }

    // O += P V  (A = P from Pt, b128 reads; B = V^T frags) — same-wave DS ordering
#pragma unroll
    for (int kc = 0; kc < 2; kc++) {
      bf16x8 ap[2];
#pragma unroll
      for (int m = 0; m < 2; m++)
        ap[m] = as_bf(*(const u16x8*)&Ptw[(m * 16 + q15) * 76 + kc * 32 + quad * 8]);
#pragma unroll
      for (int jd = 0; jd < 6; jd++)
#pragma unroll
        for (int m = 0; m < 2; m++)
          oacc[m][jd] = __builtin_amdgcn_mfma_f32_16x16x32_bf16(
              ap[m], as_bf(av[jd][kc]), oacc[m][jd], 0, 0, 0);
    }
  }

  // reduce row-sums across quads (lane holds partial for q-col n*16+q15)
  float lr[2];
#pragma unroll
  for (int n = 0; n < 2; n++) {
    float s = lsum[n];
    s += __shfl_xor(s, 16);
    s += __shfl_xor(s, 32);
    lr[n] = s;
  }

  // epilogue: oacc C-layout row q = m*16+quad*4+r, col d = jd*16+q15
#pragma unroll
  for (int m = 0; m < 2; m++) {
#pragma unroll
    for (int r = 0; r < 4; r++) {
      const float inv = 1.f / __shfl(lr[m], quad * 4 + r);
      const int trow = t0 + wq0 + m * 16 + quad * 4 + r;
#pragma unroll
      for (int jd = 0; jd < 5; jd++) {
        const int d = jd * 16 + q15;
        if (d < DHD)
          attn[(size_t)(b * TSEQ + trow) * KPW + h * DHD + d] = f2bf(oacc[m][jd][r] * inv);
      }
    }
  }
}

// ---------------- launch ----------------

extern "C" void kernel_launch(void* const* d_in, const int* in_sizes, int n_in,
                              void* d_out, int out_size, void* d_ws, size_t ws_size,
                              hipStream_t stream) {
  const float* x   = (const float*)d_in[0];
  const float* mem = (const float*)d_in[1];
  const float* Wq  = (const float*)d_in[2];
  const float* Wk  = (const float*)d_in[3];
  const float* Wv  = (const float*)d_in[4];
  const float* Wp  = (const float*)d_in[5];
  const float* bp  = (const float*)d_in[6];
  float* out = (float*)d_out;

  char* ws = (char*)d_ws;
  const size_t SZ_XMB = (size_t)2 * NR * KPW * 2;  // 39,845,888 (x rows, then mem rows)
  const size_t SZ_WT  = (size_t)3 * HD * KPW * 2;  //  2,801,664 (q|v|k rows)
  const size_t SZ_WPT = (size_t)NP3 * KPW * 2;     //    778,240
  const size_t SZ_QB  = (size_t)NR * HD * 2;       // 25,165,824

  u16* xmb    = (u16*)(ws);            // [32768][608]; dead after proj GEMMs
  u16* attn_o = (u16*)(ws);            // alias: [16384][608] padded
  u16* wt     = (u16*)(ws + SZ_XMB);   // q rows 0..767 | v 768..1535 | k 1536..2303
  u16* wp_t   = (u16*)(ws + SZ_XMB + SZ_WT);
  u16* q_buf  = (u16*)(ws + SZ_XMB + SZ_WT + SZ_WPT);
  u16* k_buf  = (u16*)(ws + SZ_XMB + SZ_WT + SZ_WPT + SZ_QB);
  u16* vt_buf = (u16*)(ws + SZ_XMB + SZ_WT + SZ_WPT + 2 * SZ_QB);
  u16* memb   = xmb + (size_t)NR * KPW;
  u16* wk_t   = wt + (size_t)2 * HD * KPW;
  // total ws use: 39.8 + 2.8 + 0.78 + 75.5 MB ~= 118.9 MB

  (void)in_sizes; (void)n_in; (void)out_size; (void)ws_size;

  // fused packs
  pack_all_kernel<<<PKA + PKB + PKC, 256, 0, stream>>>(x, mem, Wq, Wk, Wv, Wp,
                                                       xmb, wt, wp_t);

  // q+v fused projection (n-tiles 0..5 = q, 6..11 = v), then k projection
  dim3 gqv(NR / 128, 12);
  gemm_bt_kernel<3><<<gqv, 256, 0, stream>>>(xmb, wt, q_buf, vt_buf, nullptr);
  dim3 gk(NR / 128, HD / 128);
  gemm_bt_kernel<0><<<gk, 256, 0, stream>>>(memb, wk_t, k_buf, nullptr, nullptr);

  // attention (barrier-free; writes attn_o with zeroed pad, aliasing dead xmb)
  attn_kernel<<<BB * HH * (TSEQ / 128), 256, 0, stream>>>(q_buf, k_buf, vt_buf, attn_o);

  // output projection + bias -> f32 out
  dim3 g3(NR / 128, NP3 / 128);
  gemm_bt_kernel<2><<<g3, 256, 0, stream>>>(attn_o, wp_t, out, nullptr, bp);
}

// Round 7
// 296.880 us; speedup vs baseline: 1.4417x; 1.4417x over previous
//
#include <hip/hip_runtime.h>
#include <hip/hip_bf16.h>

typedef unsigned short u16;
typedef __attribute__((ext_vector_type(4))) unsigned short u16x4;
typedef __attribute__((ext_vector_type(8))) unsigned short u16x8;
typedef __attribute__((ext_vector_type(8))) __bf16 bf16x8;
typedef __attribute__((ext_vector_type(4))) float f32x4;

#define BB 16
#define TSEQ 1024
#define CC 584          /* embed dim */
#define HH 8
#define DHD 73
#define NR (BB*TSEQ)    /* 16384 rows */
#define KPW 608         /* padded K (19*32) — uniform GEMM K-loop */
#define KIT 19
#define DP 96           /* padded head dim */
#define HD (HH*DP)      /* 768 */
#define NP3 640         /* padded N for final proj */
#define PPITCH 88       /* Pt pitch: 176B rows = 16B aligned, 2-way balanced banks */
/* exp(s*584^-0.5) == exp2(s * CEXP); scores bounded -> no max subtraction */
#define CEXP 0.0596985934f

__device__ __forceinline__ u16 f2bf(float f) {
  __bf16 h = (__bf16)f;                 // native v_cvt, RNE
  return __builtin_bit_cast(u16, h);
}
__device__ __forceinline__ bf16x8 as_bf(u16x8 v) { return __builtin_bit_cast(bf16x8, v); }

/* async global->LDS, 16B/lane, LDS dst = wave-uniform base + lane*16 */
#define GLL16(g, l) __builtin_amdgcn_global_load_lds( \
    (const __attribute__((address_space(1))) void*)(g), \
    (__attribute__((address_space(3))) void*)(l), 16, 0, 0)

// ---------------- fused pack kernel ----------------
// phase A (9728 blocks):  x|mem [16384,584] f32 -> xmb [32768][608] bf16 zero-padded
// phase B (5472 blocks):  Wq/Wv/Wk -> wt [q 768 | v 768 | k 768 rows][608] bf16
// phase C (1520 blocks):  Wp -> wpt [640][608] bf16 (transposed)
#define PKA 9728
#define PKB 5472
#define PKC 1520
__global__ void pack_all_kernel(const float* __restrict__ x, const float* __restrict__ mem,
                                const float* __restrict__ Wq, const float* __restrict__ Wk,
                                const float* __restrict__ Wv, const float* __restrict__ Wp,
                                u16* __restrict__ xmb, u16* __restrict__ wt,
                                u16* __restrict__ wpt) {
  const int bidx = blockIdx.x;
  const int tid = threadIdx.x;
  if (bidx < PKA) {
    int idx = bidx * 256 + tid;
    int row = idx / (KPW / 8);
    int c8  = (idx % (KPW / 8)) * 8;
    u16x8 o = {0, 0, 0, 0, 0, 0, 0, 0};
    if (c8 < CC) {
      const float* src = (row < NR) ? &x[(size_t)row * CC + c8]
                                    : &mem[(size_t)(row - NR) * CC + c8];
      f32x4 a = *(const f32x4*)src;
      f32x4 b = *(const f32x4*)(src + 4);
#pragma unroll
      for (int t = 0; t < 4; t++) { o[t] = f2bf(a[t]); o[4 + t] = f2bf(b[t]); }
    }
    *(u16x8*)&xmb[(size_t)row * KPW + c8] = o;
  } else if (bidx < PKA + PKB) {
    int idx = (bidx - PKA) * 256 + tid;
    int w   = idx / (HD * KPW);
    int rem = idx % (HD * KPW);
    int n = rem / KPW;
    int k = rem % KPW;
    int h = n / DP, d = n % DP;
    u16 val = 0;
    if (d < DHD && k < CC) {
      const float* W = (w == 0) ? Wq : ((w == 1) ? Wv : Wk);  // order: q, v, k
      val = f2bf(W[((size_t)h * CC + k) * DHD + d]);
    }
    wt[idx] = val;
  } else {
    int idx = (bidx - PKA - PKB) * 256 + tid;
    int n = idx / KPW;
    int c = idx % KPW;
    u16 val = 0;
    if (n < CC && c < CC) val = f2bf(Wp[(size_t)c * CC + n]);
    wpt[idx] = val;
  }
}

// ---------------- bf16 GEMM (m97 structure): C[m][n] = sum_k A[m][k]*Bt[n][k] ----------
// MODE 4: merged projections. A = xmb [32768][608] (x rows 0..16383, mem rows rest).
//   x rows:  y 0..5 -> q row-major [16384][768]; y 6..11 -> v transposed
//   mem rows: y 0..5 -> k row-major [16384][768]; y 6..11 -> early exit
// MODE 2: A bf16 [M][608]; bias add, guard n < 584, store f32 [M][584]
template <int MODE>
__global__ __launch_bounds__(256) void gemm_bt_kernel(
    const u16* __restrict__ A, const u16* __restrict__ Bt,
    void* __restrict__ CoutV, void* __restrict__ CoutV2,
    const float* __restrict__ bias) {
  const int mx = blockIdx.x;
  const bool isMem = (MODE == 4) && (mx >= 128);
  if (MODE == 4 && isMem && blockIdx.y >= 6) return;
  const int m0 = mx * 128;
  const int n0 = (MODE == 4) ? ((isMem ? 1536 : 0) + blockIdx.y * 128)
                             : blockIdx.y * 128;

  __shared__ u16 As[128 * 32];
  __shared__ u16 Bs[128 * 32];
  const int tid  = threadIdx.x;
  const int lane = tid & 63;
  const int wave = tid >> 6;
  const int wm = (wave >> 1) * 64;
  const int wn = (wave & 1) * 64;
  const int q15  = lane & 15;
  const int quad = lane >> 4;

  f32x4 acc[4][4];
#pragma unroll
  for (int i = 0; i < 4; i++)
#pragma unroll
    for (int j = 0; j < 4; j++) acc[i][j] = (f32x4){0.f, 0.f, 0.f, 0.f};

  const int r0 = tid >> 2;
  const int c0 = (tid & 3) * 8;
  u16* asd0 = &As[wave * 512];
  u16* asd1 = &As[2048 + wave * 512];
  u16* bsd0 = &Bs[wave * 512];
  u16* bsd1 = &Bs[2048 + wave * 512];
  const u16* gA0 = &A[(size_t)(m0 + r0) * KPW + c0];
  const u16* gA1 = gA0 + (size_t)64 * KPW;
  const u16* gB0 = &Bt[(size_t)(n0 + r0) * KPW + c0];
  const u16* gB1 = gB0 + (size_t)64 * KPW;

  for (int kk = 0; kk < KIT; ++kk) {
    GLL16(gA0, asd0);
    GLL16(gA1, asd1);
    GLL16(gB0, bsd0);
    GLL16(gB1, bsd1);
    gA0 += 32; gA1 += 32; gB0 += 32; gB1 += 32;
    __syncthreads();
    bf16x8 af[4], bfr[4];
#pragma unroll
    for (int i = 0; i < 4; i++)
      af[i] = as_bf(*(const u16x8*)&As[(wm + i * 16 + q15) * 32 + quad * 8]);
#pragma unroll
    for (int j = 0; j < 4; j++)
      bfr[j] = as_bf(*(const u16x8*)&Bs[(wn + j * 16 + q15) * 32 + quad * 8]);
#pragma unroll
    for (int i = 0; i < 4; i++)
#pragma unroll
      for (int j = 0; j < 4; j++)
        acc[i][j] = __builtin_amdgcn_mfma_f32_16x16x32_bf16(af[i], bfr[j], acc[i][j], 0, 0, 0);
    __syncthreads();
  }

#pragma unroll
  for (int i = 0; i < 4; i++) {
#pragma unroll
    for (int j = 0; j < 4; j++) {
      const int row = m0 + wm + i * 16 + quad * 4;
      const int col = n0 + wn + j * 16 + q15;
      if (MODE == 4) {
        if (isMem) {           // k projection: mem rows, col 1536..2303 -> 0..767
          u16* Cout = (u16*)CoutV2;
          const int rk = row - NR;
          const int ck = col - 1536;
#pragma unroll
          for (int r = 0; r < 4; r++)
            Cout[(size_t)(rk + r) * HD + ck] = f2bf(acc[i][j][r]);
        } else if (col < HD) { // q projection
          u16* Cout = (u16*)CoutV;
#pragma unroll
          for (int r = 0; r < 4; r++)
            Cout[(size_t)(row + r) * HD + col] = f2bf(acc[i][j][r]);
        } else {               // v projection, transposed store
          u16* Cout = (u16*)CoutV;
          const int vn = col - HD;
          const int b  = row >> 10;
          const int tl = row & 1023;
          u16x4 pk;
#pragma unroll
          for (int r = 0; r < 4; r++) pk[r] = f2bf(acc[i][j][r]);
          *(u16x4*)&Cout[(size_t)(NR * HD) + ((size_t)(b * HD + vn)) * TSEQ + tl] = pk;
        }
      } else {
        if (col < CC) {
          float* Cout = (float*)CoutV;
          const float bv = bias[col];
#pragma unroll
          for (int r = 0; r < 4; r++)
            Cout[(size_t)(row + r) * CC + col] = acc[i][j][r] + bv;
        }
      }
    }
  }
}

// ---------------- flash attention (R5 structure + register K/V prefetch) -------------
// LDS-staged K/V; per-thread register pipeline hides global latency: tile i+1's
// chunks are loaded during tile i's compute. S^T = K·Q^T per wave -> vector Pt
// stores; wave-private Pt (pitch 88: 16B-aligned rows, balanced banks).
// q,k: [B,T,768] bf16 ; vt: [B,768,T] bf16 ; out attn: [16384][608] bf16 padded
__global__ __launch_bounds__(256, 3) void attn_kernel(
    const u16* __restrict__ qb, const u16* __restrict__ kb,
    const u16* __restrict__ vt, u16* __restrict__ attn) {
  __shared__ u16 smem[128 * 96 + 64 * 104 + 96 * 72];
  u16* Qs = smem;                       // [128][96]; later aliased by Pt
  u16* Ks = smem + 128 * 96;            // [64][104] pitch-padded
  u16* Vs = smem + 128 * 96 + 64 * 104; // [96][72]  pitch-padded
  u16* Pt = smem;                       // per-wave [32 q][pitch 88]

  const int tid  = threadIdx.x;
  const int lane = tid & 63;
  const int wave = tid >> 6;
  const int q15  = lane & 15;
  const int quad = lane >> 4;
  // XCD swizzle: bid%8 = XCD; all 8 t-tiles of one (b,h) on the same XCD
  const int bid  = blockIdx.x;
  const int loc  = bid >> 3;
  const int pair = (bid & 7) * 16 + (loc >> 3);
  const int b  = pair >> 3;
  const int h  = pair & 7;
  const int t0 = (loc & 7) * 128;
  const int wq0 = wave * 32;

  // staging geometry (per-thread constants)
  int krow[3], kc[3], vrow[3], vc[3];
#pragma unroll
  for (int p = 0; p < 3; p++) {
    int qk = tid + 256 * p;             // 0..767 over 64*12 K chunks
    krow[p] = qk / 12; kc[p] = (qk % 12) * 8;
    int qv = tid + 256 * p;             // 0..767 over 96*8 V chunks
    vrow[p] = qv / 8;  vc[p] = (qv % 8) * 8;
  }
  const u16* kbase = &kb[(size_t)(b * TSEQ) * HD + h * DP];
  const u16* vbase = &vt[(size_t)(b * HD + h * DP) * TSEQ];

  // stage Q tile [128][96]
  for (int q = tid; q < 128 * 12; q += 256) {
    int row = q / 12, c8 = (q % 12) * 8;
    *(u16x8*)&Qs[row * 96 + c8] =
        *(const u16x8*)&qb[(size_t)(b * TSEQ + t0 + row) * HD + h * DP + c8];
  }
  // zero pad cols 584..607 of this block's output rows
  if (tid < 128) {
    const u16x8 z = {0, 0, 0, 0, 0, 0, 0, 0};
    size_t base = (size_t)(b * TSEQ + t0 + tid) * KPW + CC;
    *(u16x8*)&attn[base] = z;
    *(u16x8*)&attn[base + 8] = z;
    *(u16x8*)&attn[base + 16] = z;
  }
  __syncthreads();

  // Q fragments (B-operand of S^T)
  bf16x8 aq[2][3];
#pragma unroll
  for (int n = 0; n < 2; n++)
#pragma unroll
    for (int kcx = 0; kcx < 3; kcx++)
      aq[n][kcx] = as_bf(*(const u16x8*)&Qs[(wq0 + n * 16 + q15) * 96 + kcx * 32 + quad * 8]);

  float lsum[2] = {0.f, 0.f};
  f32x4 oacc[2][6];
#pragma unroll
  for (int m = 0; m < 2; m++)
#pragma unroll
    for (int jd = 0; jd < 6; jd++) oacc[m][jd] = (f32x4){0.f, 0.f, 0.f, 0.f};

  u16* Ptw = &Pt[wave * 32 * PPITCH];

  // prefetch tile 0 into registers
  u16x8 kreg[3], vreg[3];
#pragma unroll
  for (int p = 0; p < 3; p++) {
    kreg[p] = *(const u16x8*)&kbase[(size_t)krow[p] * HD + kc[p]];
    vreg[p] = *(const u16x8*)&vbase[(size_t)vrow[p] * TSEQ + vc[p]];
  }

  for (int si = 0; si < 16; ++si) {
    // drain registers for tile si into LDS
#pragma unroll
    for (int p = 0; p < 3; p++) {
      *(u16x8*)&Ks[krow[p] * 104 + kc[p]] = kreg[p];
      *(u16x8*)&Vs[vrow[p] * 72 + vc[p]]  = vreg[p];
    }
    __syncthreads();

    // issue loads for tile si+1 (latency hidden behind compute below)
    if (si < 15) {
      const int s1 = (si + 1) * 64;
#pragma unroll
      for (int p = 0; p < 3; p++) {
        kreg[p] = *(const u16x8*)&kbase[(size_t)(s1 + krow[p]) * HD + kc[p]];
        vreg[p] = *(const u16x8*)&vbase[(size_t)vrow[p] * TSEQ + s1 + vc[p]];
      }
    }

    // S^T = K Q^T : C rows = s (4 tiles), cols = q (2 tiles)
    f32x4 st[4][2];
#pragma unroll
    for (int mt = 0; mt < 4; mt++)
#pragma unroll
      for (int n = 0; n < 2; n++) st[mt][n] = (f32x4){0.f, 0.f, 0.f, 0.f};
#pragma unroll
    for (int kcx = 0; kcx < 3; kcx++) {
      bf16x8 ak[4];
#pragma unroll
      for (int mt = 0; mt < 4; mt++)
        ak[mt] = as_bf(*(const u16x8*)&Ks[(mt * 16 + q15) * 104 + kcx * 32 + quad * 8]);
#pragma unroll
      for (int mt = 0; mt < 4; mt++)
#pragma unroll
        for (int n = 0; n < 2; n++)
          st[mt][n] = __builtin_amdgcn_mfma_f32_16x16x32_bf16(ak[mt], aq[n][kcx], st[mt][n], 0, 0, 0);
    }

    // p = exp2(s*CEXP); per-lane partial row sums; vectorized Pt store (wave-private)
#pragma unroll
    for (int mt = 0; mt < 4; mt++)
#pragma unroll
      for (int n = 0; n < 2; n++) {
        f32x4 pv;
#pragma unroll
        for (int r = 0; r < 4; r++) pv[r] = __builtin_amdgcn_exp2f(st[mt][n][r] * CEXP);
        lsum[n] += (pv[0] + pv[1]) + (pv[2] + pv[3]);
        u16x4 pk;
#pragma unroll
        for (int r = 0; r < 4; r++) pk[r] = f2bf(pv[r]);
        *(u16x4*)&Ptw[(n * 16 + q15) * PPITCH + mt * 16 + quad * 4] = pk;
      }

    // O += P V  (A = P from Pt, b128 reads; B = V^T rows) — same-wave DS ordering
#pragma unroll
    for (int kcx = 0; kcx < 2; kcx++) {
      bf16x8 ap[2];
#pragma unroll
      for (int m = 0; m < 2; m++)
        ap[m] = as_bf(*(const u16x8*)&Ptw[(m * 16 + q15) * PPITCH + kcx * 32 + quad * 8]);
#pragma unroll
      for (int jd = 0; jd < 6; jd++) {
        bf16x8 bv = as_bf(*(const u16x8*)&Vs[(jd * 16 + q15) * 72 + kcx * 32 + quad * 8]);
#pragma unroll
        for (int m = 0; m < 2; m++)
          oacc[m][jd] = __builtin_amdgcn_mfma_f32_16x16x32_bf16(ap[m], bv, oacc[m][jd], 0, 0, 0);
      }
    }
    __syncthreads();
  }

  // reduce row-sums across quads (lane holds partial for q-col n*16+q15)
  float lr[2];
#pragma unroll
  for (int n = 0; n < 2; n++) {
    float s = lsum[n];
    s += __shfl_xor(s, 16);
    s += __shfl_xor(s, 32);
    lr[n] = s;
  }

  // epilogue: oacc C-layout row q = m*16+quad*4+r, col d = jd*16+q15
#pragma unroll
  for (int m = 0; m < 2; m++) {
#pragma unroll
    for (int r = 0; r < 4; r++) {
      const float inv = 1.f / __shfl(lr[m], quad * 4 + r);
      const int trow = t0 + wq0 + m * 16 + quad * 4 + r;
#pragma unroll
      for (int jd = 0; jd < 5; jd++) {
        const int d = jd * 16 + q15;
        if (d < DHD)
          attn[(size_t)(b * TSEQ + trow) * KPW + h * DHD + d] = f2bf(oacc[m][jd][r] * inv);
      }
    }
  }
}

// ---------------- launch ----------------

extern "C" void kernel_launch(void* const* d_in, const int* in_sizes, int n_in,
                              void* d_out, int out_size, void* d_ws, size_t ws_size,
                              hipStream_t stream) {
  const float* x   = (const float*)d_in[0];
  const float* mem = (const float*)d_in[1];
  const float* Wq  = (const float*)d_in[2];
  const float* Wk  = (const float*)d_in[3];
  const float* Wv  = (const float*)d_in[4];
  const float* Wp  = (const float*)d_in[5];
  const float* bp  = (const float*)d_in[6];
  float* out = (float*)d_out;

  char* ws = (char*)d_ws;
  const size_t SZ_XMB = (size_t)2 * NR * KPW * 2;  // 39,845,888
  const size_t SZ_WT  = (size_t)3 * HD * KPW * 2;  //  2,801,664 (q|v|k rows)
  const size_t SZ_WPT = (size_t)NP3 * KPW * 2;     //    778,240
  const size_t SZ_QB  = (size_t)NR * HD * 2;       // 25,165,824

  u16* xmb    = (u16*)(ws);            // [32768][608]; dead after projections
  u16* attn_o = (u16*)(ws);            // alias: [16384][608] padded
  u16* wt     = (u16*)(ws + SZ_XMB);
  u16* wp_t   = (u16*)(ws + SZ_XMB + SZ_WT);
  u16* q_buf  = (u16*)(ws + SZ_XMB + SZ_WT + SZ_WPT);       // q then vt contiguous
  u16* vt_buf = q_buf + (size_t)NR * HD;
  u16* k_buf  = (u16*)(ws + SZ_XMB + SZ_WT + SZ_WPT + 2 * SZ_QB);
  // total ws use: 39.8 + 2.8 + 0.78 + 75.5 MB ~= 118.9 MB

  (void)in_sizes; (void)n_in; (void)out_size; (void)ws_size;

  // fused packs
  pack_all_kernel<<<PKA + PKB + PKC, 256, 0, stream>>>(x, mem, Wq, Wk, Wv, Wp,
                                                       xmb, wt, wp_t);

  // all three projections in ONE launch (x rows: q+v; mem rows: k)
  dim3 gproj(256, 12);
  gemm_bt_kernel<4><<<gproj, 256, 0, stream>>>(xmb, wt, q_buf, k_buf, nullptr);

  // attention (writes attn_o with zeroed pad, aliasing dead xmb)
  attn_kernel<<<BB * HH * (TSEQ / 128), 256, 0, stream>>>(q_buf, k_buf, vt_buf, attn_o);

  // output projection + bias -> f32 out
  dim3 g3(NR / 128, NP3 / 128);
  gemm_bt_kernel<2><<<g3, 256, 0, stream>>>(attn_o, wp_t, out, nullptr, bp);
}